// Round 11
// baseline (141.544 us; speedup 1.0000x reference)
//
#include <hip/hip_runtime.h>
#include <hip/hip_fp16.h>

// Radon forward: x [4,1,256,256] f32, thetas[180], positions[256] -> out [4,1,180,256] f32
// T=363 samples/ray (run 364; extras fall in zero border).
//
// Structure: half-split (2 z-blocks), vertical-pair f16 LDS (1 ds_read2_b32 per
// bilinear sample), support clip, 2 atomicAdds/output. Round-11 fixes:
//  - STRIDE_B 138 -> 139 (odd; even stride gave gcd(10,32)=2 -> 4-way conflicts)
//  - d-linear staging: consecutive lanes write consecutive pair-dwords
//    (conflict-free; predicated zeros replace the zero-fill pass)
//  - unroll 8 for ds_read latency cover at 1 block/CU.

#define NB   4
#define NA   180
#define NP   256
#define GANG 3
#define NSEG 4

#define STRIDE_A 261   // odd: 261 mod 32 = 5
#define ROWS_A   135
#define STRIDE_B 139   // odd: 139 mod 32 = 11  (was 138 -> 4-way conflicts)
#define ROWS_B   259
#define DW_A     (ROWS_A * STRIDE_A)          // 35235
#define DW_B     (ROWS_B * STRIDE_B)          // 36001
#define IMG_DW   DW_B
#define RED_OFF  (IMG_DW * 4)                 // 144004
#define SMEM_BYTES (RED_OFF + NP * NSEG * 4)  // 148100 <= 160KB -> 1 block/CU

__device__ __forceinline__ unsigned pack_h2(float a, float b) {
    __half2 h = __halves2half2(__float2half_rn(a), __float2half_rn(b));
    return *reinterpret_cast<unsigned*>(&h);
}

template<int STRIDE>
__device__ __forceinline__ float ray_accum(
    const unsigned int* __restrict__ imgw,
    float bxr, float byr, float nsv, float cv,
    float xlo, float xhi, float ylo, float yhi,
    int tlo, int thi, int seg)
{
    float acc = 0.f;
    int   t  = tlo + seg;
    float pxu = fmaf((float)t - 181.0f, nsv, bxr);
    float pyu = fmaf((float)t - 181.0f, cv,  byr);
    const float dpx = 4.0f * nsv;
    const float dpy = 4.0f * cv;
    #pragma unroll 8
    for (; t < thi; t += 4) {
        float px = __builtin_amdgcn_fmed3f(pxu, xlo, xhi);
        float py = __builtin_amdgcn_fmed3f(pyu, ylo, yhi);
        pxu += dpx;
        pyu += dpy;
        const float fx = floorf(px);
        const float fy = floorf(py);
        const float wx = px - fx;
        const float wy = py - fy;
        const int ad = (int)fmaf(fy, (float)STRIDE, fx);   // pair-dword index
        const unsigned q0 = imgw[ad];        // (top,bot)@col ix  -> ds_read2_b32
        const unsigned q1 = imgw[ad + 1];    // (top,bot)@col ix+1
        unsigned A = __builtin_amdgcn_perm(q1, q0, 0x05040100u);  // tops
        unsigned B = __builtin_amdgcn_perm(q1, q0, 0x07060302u);  // bottoms
        const __half2 hA = *reinterpret_cast<__half2*>(&A);
        const __half2 hB = *reinterpret_cast<__half2*>(&B);
        const __half2 wy2 = __half2half2(__float2half_rn(wy));
        const __half2 V = __hfma2(wy2, __hsub2(hB, hA), hA);
        const float vlo = __half2float(__low2half(V));
        const float vhi = __half2float(__high2half(V));
        acc = fmaf(wx, vhi - vlo, acc + vlo);
    }
    return acc;
}

extern "C" __global__ __launch_bounds__(1024)
void radon_fwd(const float* __restrict__ x,
               const float* __restrict__ thetas,
               const float* __restrict__ positions,
               float* __restrict__ out)
{
    extern __shared__ unsigned char smem[];
    unsigned int* imgw = (unsigned int*)smem;
    float*        red  = (float*)(smem + RED_OFF);

    const int grp  = blockIdx.x;
    const int b    = blockIdx.y;
    const int half = blockIdx.z;
    const int a0   = grp * GANG;
    const bool regA = (a0 < 45) || (a0 >= 135);
    const int tid = threadIdx.x + (threadIdx.y << 8);
    const float* __restrict__ xb = x + b * 65536;

    // --- d-linear staging: lane <-> consecutive pair-dword (conflict-free LDS
    //     writes); predicated zeros build the border, no zero-fill pass ---
    if (regA) {
        // P[r][c] = (img[Fb+r][c-2], img[Fb+r+1][c-2]); half0 Fb=-2, half1 Fb=122
        const int Fb = half ? 122 : -2;
        for (int d = tid; d < DW_A; d += 1024) {
            const int r  = d / STRIDE_A;
            const int c  = d - r * STRIDE_A;
            const int gc = c - 2;
            const int R0 = Fb + r, R1 = R0 + 1;
            const bool gok = ((unsigned)gc < 256u);
            const float v0 = (gok && (unsigned)R0 < 256u) ? xb[R0 * 256 + gc] : 0.f;
            const float v1 = (gok && (unsigned)R1 < 256u) ? xb[R1 * 256 + gc] : 0.f;
            imgw[d] = pack_h2(v0, v1);
        }
    } else {
        // P[r][c] = (img[r-2][col], img[r-1][col]); half0 col=c-2, half1 col=c+120
        const int cofs = half ? 120 : -2;
        for (int d = tid; d < DW_B; d += 1024) {
            const int r  = d / STRIDE_B;
            const int c  = d - r * STRIDE_B;
            const int gc = c + cofs;
            const int R0 = r - 2, R1 = r - 1;
            const bool gok = ((unsigned)gc < 256u);
            const float v0 = (gok && (unsigned)R0 < 256u) ? xb[R0 * 256 + gc] : 0.f;
            const float v1 = (gok && (unsigned)R1 < 256u) ? xb[R1 * 256 + gc] : 0.f;
            imgw[d] = pack_h2(v0, v1);
        }
    }
    __syncthreads();

    // --- clamp windows (local coords); every reachable clamp edge = zero pair ---
    float xlo, xhi, ylo, yhi, CbX, CbY;
    if (regA) {
        xlo = 0.f; xhi = 259.0f;
        ylo = 0.f; yhi = 134.984375f;
        CbX = -2.f; CbY = half ? 122.f : -2.f;
    } else {
        xlo = 0.f; xhi = 136.984375f;
        ylo = 0.f; yhi = 258.984375f;
        CbX = half ? 120.f : -2.f; CbY = -2.f;
    }

    const int   p   = threadIdx.x;
    const int   seg = threadIdx.y;
    const float s   = positions[p];

    float accs[GANG];
    for (int g = 0; g < GANG; ++g) {
        const float th  = thetas[a0 + g];
        const float cv  = cosf(th);
        const float sv  = sinf(th);
        const float nsv = -sv;
        const float bxI = fmaf(s, cv, 127.5f);
        const float byI = fmaf(s, sv, 127.5f);

        // ownership split at 128 (image coords); IDENTICAL float expr both halves
        const float slope = regA ? cv : nsv;      // |slope| >= 0.707 in regime
        const float base  = regA ? byI : bxI;
        const float tstar = 181.0f + (128.0f - base) / slope;
        const float Sf    = (slope > 0.f) ? ceilf(tstar) : (floorf(tstar) + 1.0f);
        const int   S     = (int)fmaxf(0.f, fminf(364.f, Sf));
        const bool  h0Low = (slope > 0.f);
        const int lo = ((half == 0) == h0Low) ? 0 : S;
        const int hi = ((half == 0) == h0Low) ? S : 364;

        // support clip, image window [-2,257] both axes; widened 1 sample/side
        const float msx = (fabsf(sv) < 1e-7f) ? copysignf(1e-7f, sv) : sv;
        const float mcy = (fabsf(cv) < 1e-7f) ? copysignf(1e-7f, cv) : cv;
        const float invx = -1.0f / msx;
        const float invy =  1.0f / mcy;
        const float ux1 = (-2.0f  - bxI) * invx;
        const float ux2 = (257.0f - bxI) * invx;
        const float uy1 = (-2.0f  - byI) * invy;
        const float uy2 = (257.0f - byI) * invy;
        const float ulo = fmaxf(fminf(ux1, ux2), fminf(uy1, uy2));
        const float uhi = fminf(fmaxf(ux1, ux2), fmaxf(uy1, uy2));
        const float tbf = ceilf(ulo + 181.0f) - 1.0f;
        const float tef = floorf(uhi + 181.0f) + 2.0f;
        const int tb = (int)fmaxf((float)lo, fminf(364.0f, tbf));
        const int te = (int)fminf((float)hi, fmaxf(0.0f,  tef));

        const float bxr = bxI - CbX;
        const float byr = byI - CbY;
        accs[g] = regA
            ? ray_accum<STRIDE_A>(imgw, bxr, byr, nsv, cv, xlo, xhi, ylo, yhi, tb, te, seg)
            : ray_accum<STRIDE_B>(imgw, bxr, byr, nsv, cv, xlo, xhi, ylo, yhi, tb, te, seg);
    }

    // --- reduce 4 segs, one atomicAdd per (g,p) (2 adds/output total) ---
    for (int g = 0; g < GANG; ++g) {
        __syncthreads();
        red[(seg << 8) + p] = accs[g];
        __syncthreads();
        if (seg == 0) {
            float r4 = red[p] + red[256 + p] + red[512 + p] + red[768 + p];
            atomicAdd(&out[b * (NA * NP) + (a0 + g) * NP + p], r4);
        }
    }
}

extern "C" void kernel_launch(void* const* d_in, const int* in_sizes, int n_in,
                              void* d_out, int out_size, void* d_ws, size_t ws_size,
                              hipStream_t stream) {
    const float* x         = (const float*)d_in[0];
    const float* thetas    = (const float*)d_in[1];
    const float* positions = (const float*)d_in[2];
    float* out = (float*)d_out;

    hipFuncSetAttribute((const void*)radon_fwd,
                        hipFuncAttributeMaxDynamicSharedMemorySize, SMEM_BYTES);

    hipMemsetAsync(d_out, 0, (size_t)out_size * sizeof(float), stream);

    dim3 grid(NA / GANG, NB, 2);   // 60 x 4 x 2 = 480 blocks
    dim3 block(NP, NSEG);          // 1024 threads
    radon_fwd<<<grid, block, SMEM_BYTES, stream>>>(x, thetas, positions, out);
}

// Round 12
// 104.834 us; speedup vs baseline: 1.3502x; 1.3502x over previous
//
#include <hip/hip_runtime.h>
#include <hip/hip_fp16.h>

// Radon forward: x [4,1,256,256] f32, thetas[180], positions[256] -> out [4,1,180,256] f32
// T=363 samples/ray (run 364; extras land in the zero border -> +0).
//
// Round 12 = round-8 kernel (best measured: 57.3us) with ONE change: thread
// mapping. seg = lane&3, p = wave*16 + (lane>>2): the 4 t-segments of a ray sit
// in adjacent lanes -> wave spans 16 positions (not 64) -> divergence waste from
// per-lane clip bounds shrinks ~3x; seg-reduction becomes 2 __shfl_xor adds
// (red buffer + 6 barriers deleted).

#define NB   4
#define NA   180
#define NP   256
#define GANG 3       // angles per block; regime boundaries 45,135 are multiples of 3
#define IMG_DW_MAX 17353
#define SMEM_BYTES ((IMG_DW_MAX + 1) * 4)   // 69416 B; x2 blocks = 139KB <= 160KB/CU

__device__ __forceinline__ unsigned pack_h2(float a, float b) {
    __half2 h = __halves2half2(__float2half_rn(a), __float2half_rn(b));
    return *reinterpret_cast<unsigned*>(&h);
}

template<int STRIDE_DW>
__device__ __forceinline__ float ray_accum(
    const unsigned int* __restrict__ imgw,
    float bxr, float byr, float nsv, float cv,
    float xlo, float xhi, float ylo, float yhi,
    int tlo, int thi, int seg)
{
    float acc = 0.f;
    int   t  = tlo + seg;
    float pxu = fmaf((float)t - 181.0f, nsv, bxr);
    float pyu = fmaf((float)t - 181.0f, cv,  byr);
    const float dpx = 4.0f * nsv;
    const float dpy = 4.0f * cv;
    #pragma unroll 4
    for (; t < thi; t += 4) {
        float px = __builtin_amdgcn_fmed3f(pxu, xlo, xhi);
        float py = __builtin_amdgcn_fmed3f(pyu, ylo, yhi);
        pxu += dpx;
        pyu += dpy;
        const float fx = floorf(px);
        const float fy = floorf(py);
        const float wx = px - fx;
        const float wy = py - fy;
        const int a  = (int)fmaf(fy, (float)(2 * STRIDE_DW), fx);  // half-index
        const int kd = a >> 1;
        const unsigned sh = (a & 1) << 4;
        const unsigned d0 = imgw[kd];
        const unsigned d1 = imgw[kd + 1];
        const unsigned d2 = imgw[kd + STRIDE_DW];
        const unsigned d3 = imgw[kd + STRIDE_DW + 1];
        unsigned q0 = (unsigned)(((((unsigned long long)d1) << 32) | d0) >> sh);
        unsigned q1 = (unsigned)(((((unsigned long long)d3) << 32) | d2) >> sh);
        const __half2 h0 = *reinterpret_cast<__half2*>(&q0);   // (v00, v01)
        const __half2 h1 = *reinterpret_cast<__half2*>(&q1);   // (v10, v11)
        const __half2 dv  = __hsub2(h1, h0);
        const __half2 wy2 = __half2half2(__float2half_rn(wy));
        const __half2 V   = __hfma2(wy2, dv, h0);
        const float vlo = __half2float(__low2half(V));
        const float vhi = __half2float(__high2half(V));
        acc = fmaf(wx, vhi - vlo, acc + vlo);
    }
    return acc;
}

extern "C" __global__ __launch_bounds__(1024)
void radon_fwd(const float* __restrict__ x,
               const float* __restrict__ thetas,
               const float* __restrict__ positions,
               float* __restrict__ out)
{
    extern __shared__ unsigned char smem[];
    unsigned int* imgw = (unsigned int*)smem;

    const int grp  = blockIdx.x;
    const int b    = blockIdx.y;
    const int half = blockIdx.z;
    const int a0   = grp * GANG;
    const bool regA = (a0 < 45) || (a0 >= 135);
    const int tid = threadIdx.x;                 // 0..1023
    const float* __restrict__ xb = x + b * 65536;

    // --- zero LDS image area (borders) ---
    for (int i = tid; i <= IMG_DW_MAX; i += 1024) imgw[i] = 0u;
    __syncthreads();

    // --- stage half image as f16 half2 (round-8 proven layout) ---
    if (regA) {
        // half0: img rows 0..129 -> lds rows 1..130 ; half1: img rows 126..255 -> lds rows 0..129
        const int rbase  = half ? 126 : 0;
        const int rowoff = half ? 0 : 1;
        const float2* src2 = (const float2*)(xb + rbase * 256);
        for (int j = tid; j < 130 * 128; j += 1024) {
            const int rr = j >> 7;         // 0..129
            const int k  = j & 127;        // float2 index within row
            float2 v = src2[rr * 128 + k];
            imgw[(rr + rowoff) * 131 + k + 1] = pack_h2(v.x, v.y);
        }
    } else {
        // half0: img cols 0..131 -> lds dw cols 1..66 ; half1: img cols 124..255 -> dw cols 0..65
        const int cbase2 = half ? 62 : 0;
        const int coff   = half ? 0 : 1;
        const float2* src2 = (const float2*)xb;
        for (int rr = tid >> 6; rr < 256; rr += 16) {
            for (int c2 = tid & 63; c2 < 66; c2 += 64) {
                float2 v = src2[rr * 128 + cbase2 + c2];
                imgw[(rr + 1) * 67 + c2 + coff] = pack_h2(v.x, v.y);
            }
        }
    }
    __syncthreads();

    // --- per-half clamp bounds (alloc space, rebased) — round-8 proven ---
    float xlo, xhi, ylo, yhi;
    if (regA) {
        xlo = 1.f; xhi = 258.f;
        if (half == 0) { ylo = 0.f; yhi = 129.984375f; }
        else           { ylo = 1.f; yhi = 130.f; }
    } else {
        ylo = 0.f; yhi = 257.f;
        if (half == 0) { xlo = 1.f; xhi = 130.984375f; }
        else           { xlo = 3.f; xhi = 132.f; }
    }
    const float rebY = (regA && half) ? 127.f : 0.f;
    const float rebX = (!regA && half) ? 126.f : 0.f;

    // --- NEW mapping: 4 segs of one ray in adjacent lanes ---
    const int lane = tid & 63;
    const int seg  = lane & 3;
    const int p    = ((tid >> 6) << 4) + (lane >> 2);   // 0..255
    const float s  = positions[p];

    for (int g = 0; g < GANG; ++g) {
        const float th  = thetas[a0 + g];
        const float cv  = cosf(th);
        const float sv  = sinf(th);
        const float nsv = -sv;
        const float bx2 = fmaf(s, cv, 129.5f);   // alloc-x base (col offset +2)
        const float by1 = fmaf(s, sv, 128.5f);   // alloc-y base (row offset +1)
        // ownership split: alloc(t) = base + (t-181)*slope => t* = 181 + (thr-base)/slope
        const float slope = regA ? cv : nsv;     // |slope| >= 0.707 by regime choice
        const float base  = regA ? by1 : bx2;
        const float thr   = regA ? 129.f : 130.f;
        const float tstar = 181.0f + (thr - base) / slope;
        const float Sf    = (slope > 0.f) ? ceilf(tstar) : (floorf(tstar) + 1.0f);
        const int   S     = (int)fmaxf(0.f, fminf(364.f, Sf));
        const bool  h0Low = (slope > 0.f);
        const int lo = ((half == 0) == h0Low) ? 0 : S;
        const int hi = ((half == 0) == h0Low) ? S : 364;

        // support clip (over-wide by 1 each side: skipped samples contribute 0)
        const float msx = (fabsf(sv) < 1e-7f) ? copysignf(1e-7f, sv) : sv;
        const float mcy = (fabsf(cv) < 1e-7f) ? copysignf(1e-7f, cv) : cv;
        const float invx = -1.0f / msx;
        const float invy =  1.0f / mcy;
        const float ux1 = (1.0f   - bx2) * invx;
        const float ux2 = (258.0f - bx2) * invx;
        const float uy1 = (0.0f   - by1) * invy;
        const float uy2 = (257.0f - by1) * invy;
        const float ulo = fmaxf(fminf(ux1, ux2), fminf(uy1, uy2));
        const float uhi = fminf(fmaxf(ux1, ux2), fmaxf(uy1, uy2));
        const float tbf = ceilf(ulo + 181.0f) - 1.0f;
        const float tef = floorf(uhi + 181.0f) + 2.0f;
        const int tb = (int)fmaxf((float)lo, fminf(364.0f, tbf));
        const int te = (int)fminf((float)hi, fmaxf(0.0f,  tef));

        const float bxr = bx2 - rebX;
        const float byr = by1 - rebY;
        float acc = regA
            ? ray_accum<131>(imgw, bxr, byr, nsv, cv, xlo, xhi, ylo, yhi, tb, te, seg)
            : ray_accum< 67>(imgw, bxr, byr, nsv, cv, xlo, xhi, ylo, yhi, tb, te, seg);

        // 4-seg reduction within the lane quad (deterministic butterfly)
        acc += __shfl_xor(acc, 1, 64);
        acc += __shfl_xor(acc, 2, 64);
        if (seg == 0)
            atomicAdd(&out[b * (NA * NP) + (a0 + g) * NP + p], acc);
    }
}

extern "C" void kernel_launch(void* const* d_in, const int* in_sizes, int n_in,
                              void* d_out, int out_size, void* d_ws, size_t ws_size,
                              hipStream_t stream) {
    const float* x         = (const float*)d_in[0];
    const float* thetas    = (const float*)d_in[1];
    const float* positions = (const float*)d_in[2];
    float* out = (float*)d_out;

    hipFuncSetAttribute((const void*)radon_fwd,
                        hipFuncAttributeMaxDynamicSharedMemorySize, SMEM_BYTES);

    // output accumulated via atomics -> zero it first (async, capture-safe)
    hipMemsetAsync(d_out, 0, (size_t)out_size * sizeof(float), stream);

    dim3 grid(NA / GANG, NB, 2);   // 60 x 4 x 2 = 480 blocks
    dim3 block(1024);              // 16 waves; lane quad = 4 segs of one ray
    radon_fwd<<<grid, block, SMEM_BYTES, stream>>>(x, thetas, positions, out);
}